// Round 20
// baseline (81.849 us; speedup 1.0000x reference)
//
#include <hip/hip_runtime.h>
#include <cstdint>
#include <cstddef>

// ---------------------------------------------------------------------------
// AFMADE block, incremental-exact formulation. D=16, H=1024, B=2048.
// Degree-sorted space: y[d] final after step d; h0/h1 degree-groups computed
// once. Per step s: h1 group s-1 (K=Lb(s)) -> ML += @W2g -> mu/lv[s] ->
// y[s] -> h0 group s. Block owns 16 rows; 8 waves = (net, kq).
// R20 = R18 with the GEMM split over N instead of K: wave kq owns h1 units
// nf=kq (wave0 also nf=4); accumulators ARE the final h1 -> bias+elu in
// register, direct sH1 write. sPart + reduce + one barrier deleted
// (2 barriers/step). Even/odd-kt accumulator pair halves the MFMA chain;
// 4-slot static register pipeline over kt + cross-step tail prefetch.
// All weights fragment-baked (W1f/W2f/W0f); lgkmcnt-only barriers;
// redundant ML in all waves. 2 dispatches.
// ---------------------------------------------------------------------------

#define Dd 16
#define Hh 1024
#define Bb 2048
#define EPSV 1e-12f

typedef unsigned short u16;
typedef __attribute__((ext_vector_type(4))) float f32x4;
typedef __attribute__((ext_vector_type(8))) short s16x8;
typedef __attribute__((ext_vector_type(4))) u16 u16x4;
typedef __attribute__((ext_vector_type(8))) u16 u16x8;

__device__ __forceinline__ u16 f2bf(float f) {
  union { float f; unsigned u; } v; v.f = f;
  unsigned u = v.u;
  unsigned r = (u + 0x7fffu + ((u >> 16) & 1u)) >> 16;  // RNE
  return (u16)r;
}
__device__ __forceinline__ float elu(float a) {
  return a > 0.f ? a : __expf(a) - 1.f;
}
// LDS-visibility barrier that does NOT drain vmcnt (keeps prefetches alive).
__device__ __forceinline__ void barrier_lds() {
  asm volatile("s_waitcnt lgkmcnt(0)" ::: "memory");
  __builtin_amdgcn_s_barrier();
}

// Degree-sort permutation: group g = j%15; groups 0..3 have 69, 4..14 have 68.
__device__ __forceinline__ int p_of(int i) {
  if (i < 276) { int g = i / 69, q = i - g * 69; return g + 15 * q; }
  int r = i - 276; int g = 4 + r / 68, q = r - (g - 4) * 68;
  return g + 15 * q;
}
__device__ __forceinline__ int g_of(int i) {
  return (i < 276) ? (i / 69) : (4 + (i - 276) / 68);
}
__device__ __forceinline__ int lb_of(int g) {            // prefix length
  return (g <= 4) ? 69 * g : 276 + 68 * (g - 4);
}
__device__ __forceinline__ int sz_of(int g) { return (g < 4) ? 69 : 68; }

// Fragment layouts (all pads baked ZERO), lane l = (lr = l&15, lk = l>>4):
//  W1f[net][15 g][16 kt][5 nf][2 kk][64 l][8]
//  W2f[net][15 g][3 c][64 l][8]    (K=96 used, pads zero)
//  W0f[net][15 g][5 nf][64 l][8]   (K=32, cols 16..31 zero)
//  b1p/b0p[net][15][80] f32.
#define W2F_NET (15 * 3 * 512)
#define W0F_NET (15 * 5 * 512)

// --------------------------- prep (one dispatch, 600 blocks) ---------------
__global__ __launch_bounds__(256) void prep_all(
    const float* __restrict__ mu_v0, const float* __restrict__ mu_g0,
    const float* __restrict__ mu_b0,
    const float* __restrict__ mu_v1, const float* __restrict__ mu_g1,
    const float* __restrict__ mu_b1,
    const float* __restrict__ mu_v2, const float* __restrict__ mu_g2,
    const float* __restrict__ lv_v0, const float* __restrict__ lv_g0,
    const float* __restrict__ lv_b0,
    const float* __restrict__ lv_v1, const float* __restrict__ lv_g1,
    const float* __restrict__ lv_b1,
    const float* __restrict__ lv_v2, const float* __restrict__ lv_g2,
    u16* __restrict__ W1f, u16* __restrict__ W2f, u16* __restrict__ W0f,
    float* __restrict__ b1p, float* __restrict__ b0p) {
  int bid = blockIdx.x, tid = threadIdx.x;
  int l = tid & 63, w = tid >> 6;

  {  // W1f: one wave per padded row; wid = net*1200 + g*80 + u
    int wid = bid * 4 + w;                 // 0..2399
    int net = wid / 1200, rem = wid % 1200;
    int g = rem / 80, u = rem % 80;
    u16* dstb = W1f + ((size_t)((net * 15 + g) * 16) * 10) * 512;
    const int nf = u >> 4, lane16 = u & 15;
    if (u < sz_of(g)) {
      int j = p_of(lb_of(g) + u);
      const float* v = (net ? lv_v1 : mu_v1) + (size_t)j * Hh;
      float val[4][4]; float ss = 0.f;
      for (int ii = 0; ii < 4; ++ii)
        for (int t = 0; t < 4; ++t) {
          int kp = ii * 256 + 4 * l + t;
          float xx = v[p_of(kp)];
          val[ii][t] = xx; ss += xx * xx;
        }
      for (int s = 32; s; s >>= 1) ss += __shfl_xor(ss, s);
      float sc = ((net ? lv_g1 : mu_g1)[j]) * rsqrtf(ss);
      for (int ii = 0; ii < 4; ++ii) {
        int k0 = ii * 256 + 4 * l;
        u16x4 wv;
        for (int t = 0; t < 4; ++t)
          wv[t] = f2bf((g >= g_of(k0 + t)) ? sc * val[ii][t] : 0.f);
        int kt = k0 >> 6, kk = (k0 >> 5) & 1;
        int lanep = lane16 + 16 * ((k0 & 31) >> 3);
        *(u16x4*)(dstb + (size_t)(kt * 10 + nf * 2 + kk) * 512 +
                  lanep * 8 + (k0 & 7)) = wv;
      }
      if (l == 0) b1p[wid] = (net ? lv_b1 : mu_b1)[j];
    } else {
      u16x4 z = {0, 0, 0, 0};
      for (int ii = 0; ii < 4; ++ii) {
        int k0 = ii * 256 + 4 * l;
        int kt = k0 >> 6, kk = (k0 >> 5) & 1;
        int lanep = lane16 + 16 * ((k0 & 31) >> 3);
        *(u16x4*)(dstb + (size_t)(kt * 10 + nf * 2 + kk) * 512 +
                  lanep * 8 + (k0 & 7)) = z;
      }
      if (l == 0) b1p[wid] = 0.f;
    }
  }

  if (bid < 8) {  // W2f: one wave per (net, out-row oi); frag-order writes
    int wid2 = bid * 4 + w;                // 0..31
    int nn = wid2 >> 4, oi = wid2 & 15;
    const float* v = (nn ? lv_v2 : mu_v2) + (size_t)oi * Hh;
    float ss = 0.f;
    for (int ii = 0; ii < 4; ++ii) {
      f32x4 vv = *(const f32x4*)(v + ii * 256 + 4 * l);
      ss += vv[0]*vv[0] + vv[1]*vv[1] + vv[2]*vv[2] + vv[3]*vv[3];
    }
    for (int s = 32; s; s >>= 1) ss += __shfl_xor(ss, s);
    float sc = ((nn ? lv_g2 : mu_g2)[oi]) * rsqrtf(ss);
    for (int e = l; e < 180; e += 64) {    // 15g x 3c x 4lk
      int g = e / 12, r12 = e - g * 12;
      int c = r12 >> 2, lk2 = r12 & 3;
      u16x8 wv;
      for (int t = 0; t < 8; ++t) {
        int u = c * 32 + lk2 * 8 + t;      // 0..95
        float val = (u < sz_of(g) && oi > g) ? sc * v[p_of(lb_of(g) + u)]
                                             : 0.f;
        wv[t] = f2bf(val);
      }
      *(u16x8*)(W2f + (size_t)(nn * W2F_NET) + ((g * 3 + c) * 64 +
                (oi + 16 * lk2)) * 8) = wv;
    }
  }

  if (bid >= 8 && bid < 18) {  // W0f + b0p: one thread per padded unit
    int idx = (bid - 8) * 256 + tid;       // 0..2559
    if (idx < 2400) {
      int nn = idx / 1200, rem = idx % 1200;
      int g = rem / 80, u = rem % 80;
      const int nf = u >> 4, lr16 = u & 15;
      float row[16];
      float bias = 0.f;
      if (u < sz_of(g)) {
        int j = p_of(lb_of(g) + u);
        const float* v = (nn ? lv_v0 : mu_v0) + j * Dd;
        float vv[16]; float ss = 0.f;
        for (int k = 0; k < 16; ++k) { vv[k] = v[k]; ss += vv[k] * vv[k]; }
        float sc = ((nn ? lv_g0 : mu_g0)[j]) * rsqrtf(ss);
        for (int k = 0; k < 16; ++k) row[k] = (g >= k) ? sc * vv[k] : 0.f;
        bias = (nn ? lv_b0 : mu_b0)[j];
      } else {
        for (int k = 0; k < 16; ++k) row[k] = 0.f;
      }
      for (int lk2 = 0; lk2 < 4; ++lk2) {
        u16x8 wv;
        for (int t = 0; t < 8; ++t) {
          int k = lk2 * 8 + t;
          wv[t] = f2bf((k < 16) ? row[k] : 0.f);
        }
        *(u16x8*)(W0f + (size_t)(nn * W0F_NET) + ((g * 5 + nf) * 64 +
                  (lr16 + 16 * lk2)) * 8) = wv;
      }
      b0p[nn * 1200 + g * 80 + u] = bias;
    }
  }
}

// ---- main-kernel macros (all register indices compile-time static) --------
// load W1 frags for tile KT into slot: wave's nf1 = kq; wave0 also nf=4.
#define LDW(SLOT, KT, BASE)                                                 \
  {                                                                         \
    const u16* p1_ = (BASE) + (size_t)((KT) * 10 + kq * 2) * 512 + l * 8;   \
    f1[SLOT][0] = *(const s16x8*)(p1_);                                     \
    f1[SLOT][1] = *(const s16x8*)(p1_ + 512);                               \
    if (kq == 0) {                                                          \
      const u16* p2_ = (BASE) + (size_t)((KT) * 10 + 8) * 512 + l * 8;      \
      f2[SLOT][0] = *(const s16x8*)(p2_);                                   \
      f2[SLOT][1] = *(const s16x8*)(p2_ + 512);                             \
    }                                                                       \
  }
// GEMM position KT: consume slot KT&3 (even/odd acc), prefetch KT+4.
#define POS(KT)                                                             \
  if ((KT) < ktn) {                                                         \
    s16x8 a0_ = *(const s16x8*)(&h0L[net][lr][(KT) * 64 + lk * 8]);         \
    s16x8 a1_ = *(const s16x8*)(&h0L[net][lr][(KT) * 64 + 32 + lk * 8]);    \
    if ((KT) & 1) {                                                         \
      acc1O = __builtin_amdgcn_mfma_f32_16x16x32_bf16(                      \
          a0_, f1[(KT) & 3][0], acc1O, 0, 0, 0);                            \
      acc1O = __builtin_amdgcn_mfma_f32_16x16x32_bf16(                      \
          a1_, f1[(KT) & 3][1], acc1O, 0, 0, 0);                            \
    } else {                                                                \
      acc1E = __builtin_amdgcn_mfma_f32_16x16x32_bf16(                      \
          a0_, f1[(KT) & 3][0], acc1E, 0, 0, 0);                            \
      acc1E = __builtin_amdgcn_mfma_f32_16x16x32_bf16(                      \
          a1_, f1[(KT) & 3][1], acc1E, 0, 0, 0);                            \
    }                                                                       \
    if (kq == 0) {                                                          \
      if ((KT) & 1) {                                                       \
        acc2O = __builtin_amdgcn_mfma_f32_16x16x32_bf16(                    \
            a0_, f2[(KT) & 3][0], acc2O, 0, 0, 0);                          \
        acc2O = __builtin_amdgcn_mfma_f32_16x16x32_bf16(                    \
            a1_, f2[(KT) & 3][1], acc2O, 0, 0, 0);                          \
      } else {                                                              \
        acc2E = __builtin_amdgcn_mfma_f32_16x16x32_bf16(                    \
            a0_, f2[(KT) & 3][0], acc2E, 0, 0, 0);                          \
        acc2E = __builtin_amdgcn_mfma_f32_16x16x32_bf16(                    \
            a1_, f2[(KT) & 3][1], acc2E, 0, 0, 0);                          \
      }                                                                     \
    }                                                                       \
    if ((KT) + 4 < ktn) LDW((KT) & 3, (KT) + 4, baseg);                     \
  }

// --------------------------- main (one dispatch, 128 blocks) ---------------
__global__ __launch_bounds__(512, 1) void afmade_main(
    const u16* __restrict__ W1f, const u16* __restrict__ W2f,
    const u16* __restrict__ W0f,
    const float* __restrict__ b1p, const float* __restrict__ b0p,
    const float* __restrict__ b2_mu, const float* __restrict__ b2_lv,
    const float* __restrict__ x, float* __restrict__ out) {
  __shared__ u16 h0L[2][16][1040];        // stride 2080B (~4-way aliasing)
  __shared__ u16 sH1[2][16][104];         // units 80..103 stay zero
  __shared__ u16 yb[16][40];              // cols 16..31 stay zero
  __shared__ float sX[16][16];
  __shared__ float sB1L[2400];
  __shared__ float sB0L[2400];
  __shared__ float sB2[2][16];
  __shared__ float sLsum[16];

  const int tid = threadIdx.x;
  const int l = tid & 63, w = tid >> 6;
  const int net = w >> 2, kq = w & 3;
  const int lr = l & 15, lk = l >> 4;
  const int b0g = blockIdx.x * 16;

  {  // zero-init LDS state (zeros make masked-weight products exact)
    u16x8 z = {0, 0, 0, 0, 0, 0, 0, 0};
    for (int e = tid; e < 4160; e += 512) ((u16x8*)h0L)[e] = z;
    for (int e = tid; e < 416; e += 512) ((u16x8*)sH1)[e] = z;
    for (int e = tid; e < 80; e += 512) ((u16x8*)yb)[e] = z;
  }
  for (int e = tid; e < 256; e += 512)
    sX[e >> 4][e & 15] = x[(size_t)(b0g + (e >> 4)) * 16 + (e & 15)];
  for (int e = tid; e < 2400; e += 512) { sB1L[e] = b1p[e]; sB0L[e] = b0p[e]; }
  if (tid < 16) sB2[0][tid] = b2_mu[tid];
  else if (tid < 32) sB2[1][tid - 16] = b2_lv[tid - 16];
  else if (tid < 48) sLsum[tid - 32] = 0.f;
  f32x4 mlacc0 = {0.f, 0.f, 0.f, 0.f};   // every wave: mu net ML (redundant)
  f32x4 mlacc1 = {0.f, 0.f, 0.f, 0.f};   // every wave: lv net ML (redundant)

  // 4-slot static register pipeline for this wave's W1 frags.
  s16x8 f1[4][2], f2[4][2];
  {  // prologue: step-1 (g=0, ktn=2) tiles 0,1 -> slots 0,1
    const u16* base0 = W1f + ((size_t)((net * 15 + 0) * 16) * 10) * 512 +
                       (size_t)l * 8;
    LDW(0, 0, base0);
    LDW(1, 1, base0);
  }
  __syncthreads();

  for (int s = 0; s < 16; ++s) {
    // W0 frag prefetch: contiguous 1KB loads (consumed in tail)
    s16x8 w0pre0, w0pre1;
    if (s < 15) {
      const u16* W0g = W0f + net * W0F_NET + s * (5 * 512);
      w0pre0 = *(const s16x8*)(W0g + (size_t)kq * 512 + l * 8);
      if (kq == 0)
        w0pre1 = *(const s16x8*)(W0g + (size_t)4 * 512 + l * 8);
    }

    if (s > 0) {
      const int g = s - 1;
      const int ktn = (lb_of(s) + 63) >> 6;
      const int ktnN = (s < 15) ? ((lb_of(s + 1) + 63) >> 6) : 0;
      const u16* baseg = W1f + ((size_t)((net * 15 + g) * 16) * 10) * 512 +
                         (size_t)l * 8;
      const u16* basen = W1f + ((size_t)((net * 15 + s) * 16) * 10) * 512 +
                         (size_t)l * 8;
      // ALL waves: both nets' W2 frag loads, contiguous (used after bar1)
      s16x8 w2f[6];
#pragma unroll
      for (int c = 0; c < 3; ++c) {
        w2f[c] = *(const s16x8*)(W2f + ((size_t)(g * 3 + c) * 64 + l) * 8);
        w2f[3 + c] = *(const s16x8*)(W2f + (size_t)W2F_NET +
                                     ((size_t)(g * 3 + c) * 64 + l) * 8);
      }
      // GEMM over full K for this wave's nf set; even/odd acc pair.
      f32x4 acc1E = {0.f, 0.f, 0.f, 0.f}, acc1O = {0.f, 0.f, 0.f, 0.f};
      f32x4 acc2E = {0.f, 0.f, 0.f, 0.f}, acc2O = {0.f, 0.f, 0.f, 0.f};
      POS(0)  POS(1)  POS(2)  POS(3)  POS(4)  POS(5)  POS(6)  POS(7)
      POS(8)  POS(9)  POS(10) POS(11) POS(12) POS(13) POS(14) POS(15)
      // h1 = elu(acc + b1) -> sH1 direct (this wave owns its units)
      {
        int unit = kq * 16 + lr;
        float b1v = sB1L[net * 1200 + g * 80 + unit];
        f32x4 s1 = acc1E + acc1O;
#pragma unroll
        for (int reg = 0; reg < 4; ++reg)
          sH1[net][lk * 4 + reg][unit] = f2bf(elu(s1[reg] + b1v));
        if (kq == 0) {
          int unit2 = 64 + lr;
          float b2v = sB1L[net * 1200 + g * 80 + unit2];
          f32x4 s2 = acc2E + acc2O;
#pragma unroll
          for (int reg = 0; reg < 4; ++reg)
            sH1[net][lk * 4 + reg][unit2] = f2bf(elu(s2[reg] + b2v));
        }
      }
      // tail prefetch: next step's tiles 0..3 land under the step tail
      if (s < 15) {
        LDW(0, 0, basen);
        LDW(1, 1, basen);
        if (2 < ktnN) LDW(2, 2, basen);
        if (3 < ktnN) LDW(3, 3, basen);
      }
      barrier_lds();                       // bar1 (sH1 visible)
      // ML += h1grp @ W2g^T for BOTH nets, REDUNDANT in every wave
#pragma unroll
      for (int c = 0; c < 3; ++c) {
        s16x8 a0 = *(const s16x8*)(&sH1[0][lr][c * 32 + lk * 8]);
        mlacc0 = __builtin_amdgcn_mfma_f32_16x16x32_bf16(
            a0, w2f[c], mlacc0, 0, 0, 0);
        s16x8 a1v = *(const s16x8*)(&sH1[1][lr][c * 32 + lk * 8]);
        mlacc1 = __builtin_amdgcn_mfma_f32_16x16x32_bf16(
            a1v, w2f[3 + c], mlacc1, 0, 0, 0);
      }
    }
    // y update: EVERY wave computes y (lanes lr==s hold ML column s) and
    // writes yb (identical-value benign race). out/sLsum: wave 0 only.
    if (lr == s) {
#pragma unroll
      for (int reg = 0; reg < 4; ++reg) {
        int r = lk * 4 + reg;
        float mu = mlacc0[reg] + sB2[0][s];
        float lv = mlacc1[reg] + sB2[1][s];
        float ls = 0.5f * lv;
        float yv = (sX[r][s] - mu) / (__expf(ls) + EPSV);
        yb[r][s] = f2bf(yv);
        if (w == 0) {
          out[(size_t)(b0g + r) * 16 + s] = yv;
          float ns = sLsum[r] + ls;
          sLsum[r] = ns;
          if (s == 15) out[Bb * 16 + b0g + r] = ns;
        }
      }
    }
    // in-wave LDS ordering only: each wave wrote every yb row it reads.
    asm volatile("s_waitcnt lgkmcnt(0)" ::: "memory");
    if (s < 15) {
      // h0 group s = elu(y @ W0g^T + b0) -> h0L
      const int LbS = lb_of(s), szS = sz_of(s);
      s16x8 yfrag = *(const s16x8*)(&yb[lr][lk * 8]);
      {
        int unit = kq * 16 + lr;
        f32x4 h = __builtin_amdgcn_mfma_f32_16x16x32_bf16(
            yfrag, w0pre0, (f32x4){0.f, 0.f, 0.f, 0.f}, 0, 0, 0);
        if (unit < szS) {
          float bias = sB0L[net * 1200 + s * 80 + unit];
#pragma unroll
          for (int reg = 0; reg < 4; ++reg)
            h0L[net][lk * 4 + reg][LbS + unit] = f2bf(elu(h[reg] + bias));
        }
      }
      if (kq == 0) {
        int unit = 64 + lr;
        f32x4 h = __builtin_amdgcn_mfma_f32_16x16x32_bf16(
            yfrag, w0pre1, (f32x4){0.f, 0.f, 0.f, 0.f}, 0, 0, 0);
        if (unit < szS) {
          float bias = sB0L[net * 1200 + s * 80 + unit];
#pragma unroll
          for (int reg = 0; reg < 4; ++reg)
            h0L[net][lk * 4 + reg][LbS + unit] = f2bf(elu(h[reg] + bias));
        }
      }
      barrier_lds();                       // bar2 (h0L stable)
    }
  }
}

// --------------------------- launch ----------------------------------------

extern "C" void kernel_launch(void* const* d_in, const int* in_sizes, int n_in,
                              void* d_out, int out_size, void* d_ws, size_t ws_size,
                              hipStream_t stream) {
  const float* x     = (const float*)d_in[0];
  const float* mu_v0 = (const float*)d_in[1];
  const float* mu_g0 = (const float*)d_in[2];
  const float* mu_b0 = (const float*)d_in[3];
  const float* mu_v1 = (const float*)d_in[4];
  const float* mu_g1 = (const float*)d_in[5];
  const float* mu_b1 = (const float*)d_in[6];
  const float* mu_v2 = (const float*)d_in[7];
  const float* mu_g2 = (const float*)d_in[8];
  const float* mu_b2 = (const float*)d_in[9];
  const float* lv_v0 = (const float*)d_in[10];
  const float* lv_g0 = (const float*)d_in[11];
  const float* lv_b0 = (const float*)d_in[12];
  const float* lv_v1 = (const float*)d_in[13];
  const float* lv_g1 = (const float*)d_in[14];
  const float* lv_b1 = (const float*)d_in[15];
  const float* lv_v2 = (const float*)d_in[16];
  const float* lv_g2 = (const float*)d_in[17];
  const float* lv_b2 = (const float*)d_in[18];

  char* ws = (char*)d_ws;
  u16*   W1f = (u16*)(ws);                       // 4,915,200 B
  u16*   W2f = (u16*)(ws + 4915200);             //    92,160 B
  u16*   W0f = (u16*)(ws + 5007360);             //   153,600 B
  float* b1p = (float*)(ws + 5160960);           //     9,600 B
  float* b0p = (float*)(ws + 5170560);           //     9,600 B

  prep_all<<<600, 256, 0, stream>>>(
      mu_v0, mu_g0, mu_b0, mu_v1, mu_g1, mu_b1, mu_v2, mu_g2,
      lv_v0, lv_g0, lv_b0, lv_v1, lv_g1, lv_b1, lv_v2, lv_g2,
      W1f, W2f, W0f, b1p, b0p);

  afmade_main<<<128, 512, 0, stream>>>(W1f, W2f, W0f, b1p, b0p,
                                       mu_b2, lv_b2, x, (float*)d_out);
}

// Round 21
// 71.823 us; speedup vs baseline: 1.1396x; 1.1396x over previous
//
#include <hip/hip_runtime.h>
#include <cstdint>
#include <cstddef>

// ---------------------------------------------------------------------------
// AFMADE block, incremental-exact formulation. D=16, H=1024, B=2048.
// Degree-sorted space: y[d] final after step d; h0/h1 degree-groups computed
// once. Per step s: h1 group s-1 (K=Lb(s)) -> ML += @W2g -> mu/lv[s] ->
// y[s] -> h0 group s. Block owns 16 rows; 8 waves = (net, kq 4-way K-split).
// R21 = R18 (best: 70.8us) + h0L XOR swizzle (R12-validated pattern):
// stride-1024 rows + 16B-chunk XOR (chunk ^= row&7) turns the GEMM A-read
// 4-way bank conflict into a free 2-way. All weights fragment-baked
// (W1f/W2f/W0f -> every global load is one contiguous 1KB wave-load);
// 2-slot static GEMM register pipeline with cross-step iter-0 prefetch;
// redundant ML in all 8 waves (no bar3); lgkmcnt-only barriers keep
// prefetches in flight. 2 dispatches.
// ---------------------------------------------------------------------------

#define Dd 16
#define Hh 1024
#define Bb 2048
#define EPSV 1e-12f

typedef unsigned short u16;
typedef __attribute__((ext_vector_type(4))) float f32x4;
typedef __attribute__((ext_vector_type(8))) short s16x8;
typedef __attribute__((ext_vector_type(4))) u16 u16x4;
typedef __attribute__((ext_vector_type(8))) u16 u16x8;

__device__ __forceinline__ u16 f2bf(float f) {
  union { float f; unsigned u; } v; v.f = f;
  unsigned u = v.u;
  unsigned r = (u + 0x7fffu + ((u >> 16) & 1u)) >> 16;  // RNE
  return (u16)r;
}
__device__ __forceinline__ float elu(float a) {
  return a > 0.f ? a : __expf(a) - 1.f;
}
// LDS-visibility barrier that does NOT drain vmcnt (keeps prefetches alive).
__device__ __forceinline__ void barrier_lds() {
  asm volatile("s_waitcnt lgkmcnt(0)" ::: "memory");
  __builtin_amdgcn_s_barrier();
}

// Degree-sort permutation: group g = j%15; groups 0..3 have 69, 4..14 have 68.
__device__ __forceinline__ int p_of(int i) {
  if (i < 276) { int g = i / 69, q = i - g * 69; return g + 15 * q; }
  int r = i - 276; int g = 4 + r / 68, q = r - (g - 4) * 68;
  return g + 15 * q;
}
__device__ __forceinline__ int g_of(int i) {
  return (i < 276) ? (i / 69) : (4 + (i - 276) / 68);
}
__device__ __forceinline__ int lb_of(int g) {            // prefix length
  return (g <= 4) ? 69 * g : 276 + 68 * (g - 4);
}
__device__ __forceinline__ int sz_of(int g) { return (g < 4) ? 69 : 68; }

// Fragment layouts (all pads baked ZERO), lane l = (lr = l&15, lk = l>>4):
//  W1f[net][15 g][16 kt][5 nf][2 kk][64 l][8]
//  W2f[net][15 g][3 c][64 l][8]    (K=96 used, pads zero)
//  W0f[net][15 g][5 nf][64 l][8]   (K=32, cols 16..31 zero)
//  b1p/b0p[net][15][80] f32.
#define W2F_NET (15 * 3 * 512)
#define W0F_NET (15 * 5 * 512)

// --------------------------- prep (one dispatch, 600 blocks) ---------------
__global__ __launch_bounds__(256) void prep_all(
    const float* __restrict__ mu_v0, const float* __restrict__ mu_g0,
    const float* __restrict__ mu_b0,
    const float* __restrict__ mu_v1, const float* __restrict__ mu_g1,
    const float* __restrict__ mu_b1,
    const float* __restrict__ mu_v2, const float* __restrict__ mu_g2,
    const float* __restrict__ lv_v0, const float* __restrict__ lv_g0,
    const float* __restrict__ lv_b0,
    const float* __restrict__ lv_v1, const float* __restrict__ lv_g1,
    const float* __restrict__ lv_b1,
    const float* __restrict__ lv_v2, const float* __restrict__ lv_g2,
    u16* __restrict__ W1f, u16* __restrict__ W2f, u16* __restrict__ W0f,
    float* __restrict__ b1p, float* __restrict__ b0p) {
  int bid = blockIdx.x, tid = threadIdx.x;
  int l = tid & 63, w = tid >> 6;

  {  // W1f: one wave per padded row; wid = net*1200 + g*80 + u
    int wid = bid * 4 + w;                 // 0..2399
    int net = wid / 1200, rem = wid % 1200;
    int g = rem / 80, u = rem % 80;
    u16* dstb = W1f + ((size_t)((net * 15 + g) * 16) * 10) * 512;
    const int nf = u >> 4, lane16 = u & 15;
    if (u < sz_of(g)) {
      int j = p_of(lb_of(g) + u);
      const float* v = (net ? lv_v1 : mu_v1) + (size_t)j * Hh;
      float val[4][4]; float ss = 0.f;
      for (int ii = 0; ii < 4; ++ii)
        for (int t = 0; t < 4; ++t) {
          int kp = ii * 256 + 4 * l + t;
          float xx = v[p_of(kp)];
          val[ii][t] = xx; ss += xx * xx;
        }
      for (int s = 32; s; s >>= 1) ss += __shfl_xor(ss, s);
      float sc = ((net ? lv_g1 : mu_g1)[j]) * rsqrtf(ss);
      for (int ii = 0; ii < 4; ++ii) {
        int k0 = ii * 256 + 4 * l;
        u16x4 wv;
        for (int t = 0; t < 4; ++t)
          wv[t] = f2bf((g >= g_of(k0 + t)) ? sc * val[ii][t] : 0.f);
        int kt = k0 >> 6, kk = (k0 >> 5) & 1;
        int lanep = lane16 + 16 * ((k0 & 31) >> 3);
        *(u16x4*)(dstb + (size_t)(kt * 10 + nf * 2 + kk) * 512 +
                  lanep * 8 + (k0 & 7)) = wv;
      }
      if (l == 0) b1p[wid] = (net ? lv_b1 : mu_b1)[j];
    } else {
      u16x4 z = {0, 0, 0, 0};
      for (int ii = 0; ii < 4; ++ii) {
        int k0 = ii * 256 + 4 * l;
        int kt = k0 >> 6, kk = (k0 >> 5) & 1;
        int lanep = lane16 + 16 * ((k0 & 31) >> 3);
        *(u16x4*)(dstb + (size_t)(kt * 10 + nf * 2 + kk) * 512 +
                  lanep * 8 + (k0 & 7)) = z;
      }
      if (l == 0) b1p[wid] = 0.f;
    }
  }

  if (bid < 8) {  // W2f: one wave per (net, out-row oi); frag-order writes
    int wid2 = bid * 4 + w;                // 0..31
    int nn = wid2 >> 4, oi = wid2 & 15;
    const float* v = (nn ? lv_v2 : mu_v2) + (size_t)oi * Hh;
    float ss = 0.f;
    for (int ii = 0; ii < 4; ++ii) {
      f32x4 vv = *(const f32x4*)(v + ii * 256 + 4 * l);
      ss += vv[0]*vv[0] + vv[1]*vv[1] + vv[2]*vv[2] + vv[3]*vv[3];
    }
    for (int s = 32; s; s >>= 1) ss += __shfl_xor(ss, s);
    float sc = ((nn ? lv_g2 : mu_g2)[oi]) * rsqrtf(ss);
    for (int e = l; e < 180; e += 64) {    // 15g x 3c x 4lk
      int g = e / 12, r12 = e - g * 12;
      int c = r12 >> 2, lk2 = r12 & 3;
      u16x8 wv;
      for (int t = 0; t < 8; ++t) {
        int u = c * 32 + lk2 * 8 + t;      // 0..95
        float val = (u < sz_of(g) && oi > g) ? sc * v[p_of(lb_of(g) + u)]
                                             : 0.f;
        wv[t] = f2bf(val);
      }
      *(u16x8*)(W2f + (size_t)(nn * W2F_NET) + ((g * 3 + c) * 64 +
                (oi + 16 * lk2)) * 8) = wv;
    }
  }

  if (bid >= 8 && bid < 18) {  // W0f + b0p: one thread per padded unit
    int idx = (bid - 8) * 256 + tid;       // 0..2559
    if (idx < 2400) {
      int nn = idx / 1200, rem = idx % 1200;
      int g = rem / 80, u = rem % 80;
      const int nf = u >> 4, lr16 = u & 15;
      float row[16];
      float bias = 0.f;
      if (u < sz_of(g)) {
        int j = p_of(lb_of(g) + u);
        const float* v = (nn ? lv_v0 : mu_v0) + j * Dd;
        float vv[16]; float ss = 0.f;
        for (int k = 0; k < 16; ++k) { vv[k] = v[k]; ss += vv[k] * vv[k]; }
        float sc = ((nn ? lv_g0 : mu_g0)[j]) * rsqrtf(ss);
        for (int k = 0; k < 16; ++k) row[k] = (g >= k) ? sc * vv[k] : 0.f;
        bias = (nn ? lv_b0 : mu_b0)[j];
      } else {
        for (int k = 0; k < 16; ++k) row[k] = 0.f;
      }
      for (int lk2 = 0; lk2 < 4; ++lk2) {
        u16x8 wv;
        for (int t = 0; t < 8; ++t) {
          int k = lk2 * 8 + t;
          wv[t] = f2bf((k < 16) ? row[k] : 0.f);
        }
        *(u16x8*)(W0f + (size_t)(nn * W0F_NET) + ((g * 5 + nf) * 64 +
                  (lr16 + 16 * lk2)) * 8) = wv;
      }
      b0p[nn * 1200 + g * 80 + u] = bias;
    }
  }
}

// fragment load / mfma helper macros (all register indices compile-time)
#define LOADF(DST, BASE, KT)                                                \
  {                                                                         \
    const u16* fp_ = (BASE) + (size_t)(KT) * 5120;                          \
    _Pragma("unroll") for (int nf_ = 0; nf_ < 5; ++nf_)                     \
      _Pragma("unroll") for (int kk_ = 0; kk_ < 2; ++kk_)                   \
        DST[nf_][kk_] = *(const s16x8*)(fp_ + (nf_ * 2 + kk_) * 512);       \
  }
// A-reads from XOR-swizzled h0L: chunk c = kt*8 + {lk, 4+lk}, c ^= lr&7.
#define MFMAI(SLOT, KT)                                                     \
  {                                                                         \
    int c0_ = (((KT) * 8 + lk) ^ (lr & 7)) << 3;                            \
    int c1_ = (((KT) * 8 + 4 + lk) ^ (lr & 7)) << 3;                        \
    s16x8 a0_ = *(const s16x8*)(&h0L[net][lr * 1024 + c0_]);                \
    s16x8 a1_ = *(const s16x8*)(&h0L[net][lr * 1024 + c1_]);                \
    _Pragma("unroll") for (int nf_ = 0; nf_ < 5; ++nf_) {                   \
      hacc[nf_] = __builtin_amdgcn_mfma_f32_16x16x32_bf16(                  \
          a0_, SLOT[nf_][0], hacc[nf_], 0, 0, 0);                           \
      hacc[nf_] = __builtin_amdgcn_mfma_f32_16x16x32_bf16(                  \
          a1_, SLOT[nf_][1], hacc[nf_], 0, 0, 0);                           \
    }                                                                       \
  }

// --------------------------- main (one dispatch, 128 blocks) ---------------
__global__ __launch_bounds__(512, 1) void afmade_main(
    const u16* __restrict__ W1f, const u16* __restrict__ W2f,
    const u16* __restrict__ W0f,
    const float* __restrict__ b1p, const float* __restrict__ b0p,
    const float* __restrict__ b2_mu, const float* __restrict__ b2_lv,
    const float* __restrict__ x, float* __restrict__ out) {
  __shared__ u16 h0L[2][16 * 1024];       // 64 KB, 16B-chunk XOR swizzle
  __shared__ float sPart[2][4][16][80];   // 40 KB
  __shared__ u16 sH1[2][16][104];         // units 80..95 stay zero
  __shared__ u16 yb[16][40];              // cols 16..31 stay zero
  __shared__ float sX[16][16];
  __shared__ float sB1L[2400];
  __shared__ float sB0L[2400];
  __shared__ float sB2[2][16];
  __shared__ float sLsum[16];

  const int tid = threadIdx.x;
  const int l = tid & 63, w = tid >> 6;
  const int net = w >> 2, kq = w & 3;
  const int lr = l & 15, lk = l >> 4;
  const int b0g = blockIdx.x * 16;

  {  // zero-init LDS state (zeros make masked-weight products exact;
     // swizzle is a per-row bijection so linear zeroing is fine)
    u16x8 z = {0, 0, 0, 0, 0, 0, 0, 0};
    for (int e = tid; e < 4096; e += 512) ((u16x8*)h0L)[e] = z;
    for (int e = tid; e < 416; e += 512) ((u16x8*)sH1)[e] = z;
    for (int e = tid; e < 80; e += 512) ((u16x8*)yb)[e] = z;
  }
  for (int e = tid; e < 256; e += 512)
    sX[e >> 4][e & 15] = x[(size_t)(b0g + (e >> 4)) * 16 + (e & 15)];
  for (int e = tid; e < 2400; e += 512) { sB1L[e] = b1p[e]; sB0L[e] = b0p[e]; }
  if (tid < 16) sB2[0][tid] = b2_mu[tid];
  else if (tid < 32) sB2[1][tid - 16] = b2_lv[tid - 16];
  else if (tid < 48) sLsum[tid - 32] = 0.f;
  f32x4 mlacc0 = {0.f, 0.f, 0.f, 0.f};   // every wave: mu net ML (redundant)
  f32x4 mlacc1 = {0.f, 0.f, 0.f, 0.f};   // every wave: lv net ML (redundant)

  // 2-slot static register pipeline for W1 B-frags (R14-proven parity).
  s16x8 bfA[5][2], bfB[5][2];
  {  // prologue: step-1 (g=0, ktn=2) iter-0 -> A
    const u16* base1 = W1f + ((size_t)((net * 15 + 0) * 16) * 10) * 512 +
                       (size_t)l * 8;
    if (kq < 2) LOADF(bfA, base1, kq);
  }
  __syncthreads();

  for (int s = 0; s < 16; ++s) {
    // W0 frag prefetch: contiguous 1KB loads (consumed in tail)
    s16x8 w0pre0, w0pre1;
    if (s < 15) {
      const u16* W0g = W0f + net * W0F_NET + s * (5 * 512);
      w0pre0 = *(const s16x8*)(W0g + (size_t)kq * 512 + l * 8);
      if (kq == 0)
        w0pre1 = *(const s16x8*)(W0g + (size_t)4 * 512 + l * 8);
    }

    if (s > 0) {
      const int g = s - 1;
      const int ktn = (lb_of(s) + 63) >> 6;
      const int ktnN = (s < 15) ? ((lb_of(s + 1) + 63) >> 6) : 0;
      const u16* baseg = W1f + ((size_t)((net * 15 + g) * 16) * 10) * 512 +
                         (size_t)l * 8;
      const u16* basen = W1f + ((size_t)((net * 15 + s) * 16) * 10) * 512 +
                         (size_t)l * 8;
      // ALL waves: both nets' W2 frag loads, contiguous (used after bar2)
      s16x8 w2f[6];
#pragma unroll
      for (int c = 0; c < 3; ++c) {
        w2f[c] = *(const s16x8*)(W2f + ((size_t)(g * 3 + c) * 64 + l) * 8);
        w2f[3 + c] = *(const s16x8*)(W2f + (size_t)W2F_NET +
                                     ((size_t)(g * 3 + c) * 64 + l) * 8);
      }
      // GEMM, slots alternate A/B; i+1 prefetch issued at position i.
      f32x4 hacc[5] = {};
      if (kq + 4 < ktn)  LOADF(bfB, baseg, kq + 4);
      if (kq < ktn)      MFMAI(bfA, kq);
      if (kq + 8 < ktn)  LOADF(bfA, baseg, kq + 8);
      if (kq + 4 < ktn)  MFMAI(bfB, kq + 4);
      if (kq + 12 < ktn) LOADF(bfB, baseg, kq + 12);
      if (kq + 8 < ktn)  MFMAI(bfA, kq + 8);
      if (kq + 12 < ktn) MFMAI(bfB, kq + 12);
      // write partials
#pragma unroll
      for (int nf = 0; nf < 5; ++nf)
#pragma unroll
        for (int reg = 0; reg < 4; ++reg)
          sPart[net][kq][lk * 4 + reg][nf * 16 + lr] = hacc[nf][reg];
      // tail prefetch: next step's iter-0 lands under the step tail
      if (s < 15 && kq < ktnN) LOADF(bfA, basen, kq);
      barrier_lds();                       // bar1 (sPart visible)
      // reduce 4 partials + bias + elu -> sH1 (div-free mapping, 5/thread)
      {
        const int nn = tid >> 8;
        const int rr = (tid >> 4) & 15;
        const int u0 = tid & 15;
#pragma unroll
        for (int c = 0; c < 5; ++c) {
          int uu = c * 16 + u0;
          float v = sPart[nn][0][rr][uu] + sPart[nn][1][rr][uu] +
                    sPart[nn][2][rr][uu] + sPart[nn][3][rr][uu] +
                    sB1L[nn * 1200 + g * 80 + uu];
          sH1[nn][rr][uu] = f2bf(elu(v));
        }
      }
      barrier_lds();                       // bar2 (sH1 visible)
      // ML += h1grp @ W2g^T for BOTH nets, REDUNDANT in every wave
#pragma unroll
      for (int c = 0; c < 3; ++c) {
        s16x8 a0 = *(const s16x8*)(&sH1[0][lr][c * 32 + lk * 8]);
        mlacc0 = __builtin_amdgcn_mfma_f32_16x16x32_bf16(
            a0, w2f[c], mlacc0, 0, 0, 0);
        s16x8 a1v = *(const s16x8*)(&sH1[1][lr][c * 32 + lk * 8]);
        mlacc1 = __builtin_amdgcn_mfma_f32_16x16x32_bf16(
            a1v, w2f[3 + c], mlacc1, 0, 0, 0);
      }
    }
    // y update: EVERY wave computes y (lanes lr==s hold ML column s) and
    // writes yb (identical-value benign race). out/sLsum: wave 0 only.
    if (lr == s) {
#pragma unroll
      for (int reg = 0; reg < 4; ++reg) {
        int r = lk * 4 + reg;
        float mu = mlacc0[reg] + sB2[0][s];
        float lv = mlacc1[reg] + sB2[1][s];
        float ls = 0.5f * lv;
        float yv = (sX[r][s] - mu) / (__expf(ls) + EPSV);
        yb[r][s] = f2bf(yv);
        if (w == 0) {
          out[(size_t)(b0g + r) * 16 + s] = yv;
          float ns = sLsum[r] + ls;
          sLsum[r] = ns;
          if (s == 15) out[Bb * 16 + b0g + r] = ns;
        }
      }
    }
    // in-wave LDS ordering only: each wave wrote every yb row it reads.
    asm volatile("s_waitcnt lgkmcnt(0)" ::: "memory");
    if (s < 15) {
      // h0 group s = elu(y @ W0g^T + b0) -> h0L (swizzled scatter writes)
      const int LbS = lb_of(s), szS = sz_of(s);
      s16x8 yfrag = *(const s16x8*)(&yb[lr][lk * 8]);
      {
        int unit = kq * 16 + lr;
        f32x4 h = __builtin_amdgcn_mfma_f32_16x16x32_bf16(
            yfrag, w0pre0, (f32x4){0.f, 0.f, 0.f, 0.f}, 0, 0, 0);
        if (unit < szS) {
          float bias = sB0L[net * 1200 + s * 80 + unit];
          int col = LbS + unit;
#pragma unroll
          for (int reg = 0; reg < 4; ++reg) {
            int row = lk * 4 + reg;
            int idx = row * 1024 +
                      ((((col >> 3) ^ (row & 7)) << 3) | (col & 7));
            h0L[net][idx] = f2bf(elu(h[reg] + bias));
          }
        }
      }
      if (kq == 0) {
        int unit = 64 + lr;
        f32x4 h = __builtin_amdgcn_mfma_f32_16x16x32_bf16(
            yfrag, w0pre1, (f32x4){0.f, 0.f, 0.f, 0.f}, 0, 0, 0);
        if (unit < szS) {
          float bias = sB0L[net * 1200 + s * 80 + unit];
          int col = LbS + unit;
#pragma unroll
          for (int reg = 0; reg < 4; ++reg) {
            int row = lk * 4 + reg;
            int idx = row * 1024 +
                      ((((col >> 3) ^ (row & 7)) << 3) | (col & 7));
            h0L[net][idx] = f2bf(elu(h[reg] + bias));
          }
        }
      }
      barrier_lds();                       // bar4 (h0L stable)
    }
  }
}

// --------------------------- launch ----------------------------------------

extern "C" void kernel_launch(void* const* d_in, const int* in_sizes, int n_in,
                              void* d_out, int out_size, void* d_ws, size_t ws_size,
                              hipStream_t stream) {
  const float* x     = (const float*)d_in[0];
  const float* mu_v0 = (const float*)d_in[1];
  const float* mu_g0 = (const float*)d_in[2];
  const float* mu_b0 = (const float*)d_in[3];
  const float* mu_v1 = (const float*)d_in[4];
  const float* mu_g1 = (const float*)d_in[5];
  const float* mu_b1 = (const float*)d_in[6];
  const float* mu_v2 = (const float*)d_in[7];
  const float* mu_g2 = (const float*)d_in[8];
  const float* mu_b2 = (const float*)d_in[9];
  const float* lv_v0 = (const float*)d_in[10];
  const float* lv_g0 = (const float*)d_in[11];
  const float* lv_b0 = (const float*)d_in[12];
  const float* lv_v1 = (const float*)d_in[13];
  const float* lv_g1 = (const float*)d_in[14];
  const float* lv_b1 = (const float*)d_in[15];
  const float* lv_v2 = (const float*)d_in[16];
  const float* lv_g2 = (const float*)d_in[17];
  const float* lv_b2 = (const float*)d_in[18];

  char* ws = (char*)d_ws;
  u16*   W1f = (u16*)(ws);                       // 4,915,200 B
  u16*   W2f = (u16*)(ws + 4915200);             //    92,160 B
  u16*   W0f = (u16*)(ws + 5007360);             //   153,600 B
  float* b1p = (float*)(ws + 5160960);           //     9,600 B
  float* b0p = (float*)(ws + 5170560);           //     9,600 B

  prep_all<<<600, 256, 0, stream>>>(
      mu_v0, mu_g0, mu_b0, mu_v1, mu_g1, mu_b1, mu_v2, mu_g2,
      lv_v0, lv_g0, lv_b0, lv_v1, lv_g1, lv_b1, lv_v2, lv_g2,
      W1f, W2f, W0f, b1p, b0p);

  afmade_main<<<128, 512, 0, stream>>>(W1f, W2f, W0f, b1p, b0p,
                                       mu_b2, lv_b2, x, (float*)d_out);
}

// Round 22
// 70.380 us; speedup vs baseline: 1.1630x; 1.0205x over previous
//
#include <hip/hip_runtime.h>
#include <cstdint>
#include <cstddef>

// ---------------------------------------------------------------------------
// AFMADE block, incremental-exact formulation. D=16, H=1024, B=2048.
// Degree-sorted space: y[d] final after step d; h0/h1 degree-groups computed
// once. Per step s: h1 group s-1 (K=Lb(s)) -> ML += @W2g -> mu/lv[s] ->
// y[s] -> h0 group s. Block owns 16 rows; 8 waves = (net, kq 4-way K-split).
// FINAL (R18, best measured 70.8us): all weights baked in MFMA fragment
// order (W1f/W2f/W0f) so every global load in the main loop is one
// contiguous 1KB wave-load; 2-slot static GEMM register pipeline with
// cross-step iter-0 tail prefetch; redundant ML in all 8 waves (no bar3);
// lgkmcnt-only barriers keep prefetches in flight. 2 dispatches.
// ---------------------------------------------------------------------------

#define Dd 16
#define Hh 1024
#define Bb 2048
#define EPSV 1e-12f

typedef unsigned short u16;
typedef __attribute__((ext_vector_type(4))) float f32x4;
typedef __attribute__((ext_vector_type(8))) short s16x8;
typedef __attribute__((ext_vector_type(4))) u16 u16x4;
typedef __attribute__((ext_vector_type(8))) u16 u16x8;

__device__ __forceinline__ u16 f2bf(float f) {
  union { float f; unsigned u; } v; v.f = f;
  unsigned u = v.u;
  unsigned r = (u + 0x7fffu + ((u >> 16) & 1u)) >> 16;  // RNE
  return (u16)r;
}
__device__ __forceinline__ float elu(float a) {
  return a > 0.f ? a : __expf(a) - 1.f;
}
// LDS-visibility barrier that does NOT drain vmcnt (keeps prefetches alive).
__device__ __forceinline__ void barrier_lds() {
  asm volatile("s_waitcnt lgkmcnt(0)" ::: "memory");
  __builtin_amdgcn_s_barrier();
}

// Degree-sort permutation: group g = j%15; groups 0..3 have 69, 4..14 have 68.
__device__ __forceinline__ int p_of(int i) {
  if (i < 276) { int g = i / 69, q = i - g * 69; return g + 15 * q; }
  int r = i - 276; int g = 4 + r / 68, q = r - (g - 4) * 68;
  return g + 15 * q;
}
__device__ __forceinline__ int g_of(int i) {
  return (i < 276) ? (i / 69) : (4 + (i - 276) / 68);
}
__device__ __forceinline__ int lb_of(int g) {            // prefix length
  return (g <= 4) ? 69 * g : 276 + 68 * (g - 4);
}
__device__ __forceinline__ int sz_of(int g) { return (g < 4) ? 69 : 68; }

// Fragment layouts (all pads baked ZERO), lane l = (lr = l&15, lk = l>>4):
//  W1f[net][15 g][16 kt][5 nf][2 kk][64 l][8]
//  W2f[net][15 g][3 c][64 l][8]    (K=96 used, pads zero)
//  W0f[net][15 g][5 nf][64 l][8]   (K=32, cols 16..31 zero)
//  b1p/b0p[net][15][80] f32.
#define W2F_NET (15 * 3 * 512)
#define W0F_NET (15 * 5 * 512)

// --------------------------- prep (one dispatch, 600 blocks) ---------------
__global__ __launch_bounds__(256) void prep_all(
    const float* __restrict__ mu_v0, const float* __restrict__ mu_g0,
    const float* __restrict__ mu_b0,
    const float* __restrict__ mu_v1, const float* __restrict__ mu_g1,
    const float* __restrict__ mu_b1,
    const float* __restrict__ mu_v2, const float* __restrict__ mu_g2,
    const float* __restrict__ lv_v0, const float* __restrict__ lv_g0,
    const float* __restrict__ lv_b0,
    const float* __restrict__ lv_v1, const float* __restrict__ lv_g1,
    const float* __restrict__ lv_b1,
    const float* __restrict__ lv_v2, const float* __restrict__ lv_g2,
    u16* __restrict__ W1f, u16* __restrict__ W2f, u16* __restrict__ W0f,
    float* __restrict__ b1p, float* __restrict__ b0p) {
  int bid = blockIdx.x, tid = threadIdx.x;
  int l = tid & 63, w = tid >> 6;

  {  // W1f: one wave per padded row; wid = net*1200 + g*80 + u
    int wid = bid * 4 + w;                 // 0..2399
    int net = wid / 1200, rem = wid % 1200;
    int g = rem / 80, u = rem % 80;
    u16* dstb = W1f + ((size_t)((net * 15 + g) * 16) * 10) * 512;
    const int nf = u >> 4, lane16 = u & 15;
    if (u < sz_of(g)) {
      int j = p_of(lb_of(g) + u);
      const float* v = (net ? lv_v1 : mu_v1) + (size_t)j * Hh;
      float val[4][4]; float ss = 0.f;
      for (int ii = 0; ii < 4; ++ii)
        for (int t = 0; t < 4; ++t) {
          int kp = ii * 256 + 4 * l + t;
          float xx = v[p_of(kp)];
          val[ii][t] = xx; ss += xx * xx;
        }
      for (int s = 32; s; s >>= 1) ss += __shfl_xor(ss, s);
      float sc = ((net ? lv_g1 : mu_g1)[j]) * rsqrtf(ss);
      for (int ii = 0; ii < 4; ++ii) {
        int k0 = ii * 256 + 4 * l;
        u16x4 wv;
        for (int t = 0; t < 4; ++t)
          wv[t] = f2bf((g >= g_of(k0 + t)) ? sc * val[ii][t] : 0.f);
        int kt = k0 >> 6, kk = (k0 >> 5) & 1;
        int lanep = lane16 + 16 * ((k0 & 31) >> 3);
        *(u16x4*)(dstb + (size_t)(kt * 10 + nf * 2 + kk) * 512 +
                  lanep * 8 + (k0 & 7)) = wv;
      }
      if (l == 0) b1p[wid] = (net ? lv_b1 : mu_b1)[j];
    } else {
      u16x4 z = {0, 0, 0, 0};
      for (int ii = 0; ii < 4; ++ii) {
        int k0 = ii * 256 + 4 * l;
        int kt = k0 >> 6, kk = (k0 >> 5) & 1;
        int lanep = lane16 + 16 * ((k0 & 31) >> 3);
        *(u16x4*)(dstb + (size_t)(kt * 10 + nf * 2 + kk) * 512 +
                  lanep * 8 + (k0 & 7)) = z;
      }
      if (l == 0) b1p[wid] = 0.f;
    }
  }

  if (bid < 8) {  // W2f: one wave per (net, out-row oi); frag-order writes
    int wid2 = bid * 4 + w;                // 0..31
    int nn = wid2 >> 4, oi = wid2 & 15;
    const float* v = (nn ? lv_v2 : mu_v2) + (size_t)oi * Hh;
    float ss = 0.f;
    for (int ii = 0; ii < 4; ++ii) {
      f32x4 vv = *(const f32x4*)(v + ii * 256 + 4 * l);
      ss += vv[0]*vv[0] + vv[1]*vv[1] + vv[2]*vv[2] + vv[3]*vv[3];
    }
    for (int s = 32; s; s >>= 1) ss += __shfl_xor(ss, s);
    float sc = ((nn ? lv_g2 : mu_g2)[oi]) * rsqrtf(ss);
    for (int e = l; e < 180; e += 64) {    // 15g x 3c x 4lk
      int g = e / 12, r12 = e - g * 12;
      int c = r12 >> 2, lk2 = r12 & 3;
      u16x8 wv;
      for (int t = 0; t < 8; ++t) {
        int u = c * 32 + lk2 * 8 + t;      // 0..95
        float val = (u < sz_of(g) && oi > g) ? sc * v[p_of(lb_of(g) + u)]
                                             : 0.f;
        wv[t] = f2bf(val);
      }
      *(u16x8*)(W2f + (size_t)(nn * W2F_NET) + ((g * 3 + c) * 64 +
                (oi + 16 * lk2)) * 8) = wv;
    }
  }

  if (bid >= 8 && bid < 18) {  // W0f + b0p: one thread per padded unit
    int idx = (bid - 8) * 256 + tid;       // 0..2559
    if (idx < 2400) {
      int nn = idx / 1200, rem = idx % 1200;
      int g = rem / 80, u = rem % 80;
      const int nf = u >> 4, lr16 = u & 15;
      float row[16];
      float bias = 0.f;
      if (u < sz_of(g)) {
        int j = p_of(lb_of(g) + u);
        const float* v = (nn ? lv_v0 : mu_v0) + j * Dd;
        float vv[16]; float ss = 0.f;
        for (int k = 0; k < 16; ++k) { vv[k] = v[k]; ss += vv[k] * vv[k]; }
        float sc = ((nn ? lv_g0 : mu_g0)[j]) * rsqrtf(ss);
        for (int k = 0; k < 16; ++k) row[k] = (g >= k) ? sc * vv[k] : 0.f;
        bias = (nn ? lv_b0 : mu_b0)[j];
      } else {
        for (int k = 0; k < 16; ++k) row[k] = 0.f;
      }
      for (int lk2 = 0; lk2 < 4; ++lk2) {
        u16x8 wv;
        for (int t = 0; t < 8; ++t) {
          int k = lk2 * 8 + t;
          wv[t] = f2bf((k < 16) ? row[k] : 0.f);
        }
        *(u16x8*)(W0f + (size_t)(nn * W0F_NET) + ((g * 5 + nf) * 64 +
                  (lr16 + 16 * lk2)) * 8) = wv;
      }
      b0p[nn * 1200 + g * 80 + u] = bias;
    }
  }
}

// fragment load / mfma helper macros (all register indices compile-time)
#define LOADF(DST, BASE, KT)                                                \
  {                                                                         \
    const u16* fp_ = (BASE) + (size_t)(KT) * 5120;                          \
    _Pragma("unroll") for (int nf_ = 0; nf_ < 5; ++nf_)                     \
      _Pragma("unroll") for (int kk_ = 0; kk_ < 2; ++kk_)                   \
        DST[nf_][kk_] = *(const s16x8*)(fp_ + (nf_ * 2 + kk_) * 512);       \
  }
#define MFMAI(SLOT, KT)                                                     \
  {                                                                         \
    s16x8 a0_ = *(const s16x8*)(&h0L[net][lr][(KT) * 64 + lk * 8]);         \
    s16x8 a1_ = *(const s16x8*)(&h0L[net][lr][(KT) * 64 + 32 + lk * 8]);    \
    _Pragma("unroll") for (int nf_ = 0; nf_ < 5; ++nf_) {                   \
      hacc[nf_] = __builtin_amdgcn_mfma_f32_16x16x32_bf16(                  \
          a0_, SLOT[nf_][0], hacc[nf_], 0, 0, 0);                           \
      hacc[nf_] = __builtin_amdgcn_mfma_f32_16x16x32_bf16(                  \
          a1_, SLOT[nf_][1], hacc[nf_], 0, 0, 0);                           \
    }                                                                       \
  }

// --------------------------- main (one dispatch, 128 blocks) ---------------
__global__ __launch_bounds__(512, 1) void afmade_main(
    const u16* __restrict__ W1f, const u16* __restrict__ W2f,
    const u16* __restrict__ W0f,
    const float* __restrict__ b1p, const float* __restrict__ b0p,
    const float* __restrict__ b2_mu, const float* __restrict__ b2_lv,
    const float* __restrict__ x, float* __restrict__ out) {
  __shared__ u16 h0L[2][16][1040];        // stride 2080B (~4-way aliasing)
  __shared__ float sPart[2][4][16][80];   // 40 KB
  __shared__ u16 sH1[2][16][104];         // units 80..95 stay zero
  __shared__ u16 yb[16][40];              // cols 16..31 stay zero
  __shared__ float sX[16][16];
  __shared__ float sB1L[2400];
  __shared__ float sB0L[2400];
  __shared__ float sB2[2][16];
  __shared__ float sLsum[16];

  const int tid = threadIdx.x;
  const int l = tid & 63, w = tid >> 6;
  const int net = w >> 2, kq = w & 3;
  const int lr = l & 15, lk = l >> 4;
  const int b0g = blockIdx.x * 16;

  {  // zero-init LDS state (zeros make masked-weight products exact)
    u16x8 z = {0, 0, 0, 0, 0, 0, 0, 0};
    for (int e = tid; e < 4160; e += 512) ((u16x8*)h0L)[e] = z;
    for (int e = tid; e < 416; e += 512) ((u16x8*)sH1)[e] = z;
    for (int e = tid; e < 80; e += 512) ((u16x8*)yb)[e] = z;
  }
  for (int e = tid; e < 256; e += 512)
    sX[e >> 4][e & 15] = x[(size_t)(b0g + (e >> 4)) * 16 + (e & 15)];
  for (int e = tid; e < 2400; e += 512) { sB1L[e] = b1p[e]; sB0L[e] = b0p[e]; }
  if (tid < 16) sB2[0][tid] = b2_mu[tid];
  else if (tid < 32) sB2[1][tid - 16] = b2_lv[tid - 16];
  else if (tid < 48) sLsum[tid - 32] = 0.f;
  f32x4 mlacc0 = {0.f, 0.f, 0.f, 0.f};   // every wave: mu net ML (redundant)
  f32x4 mlacc1 = {0.f, 0.f, 0.f, 0.f};   // every wave: lv net ML (redundant)

  // 2-slot static register pipeline for W1 B-frags (R14-proven parity).
  s16x8 bfA[5][2], bfB[5][2];
  {  // prologue: step-1 (g=0, ktn=2) iter-0 -> A
    const u16* base1 = W1f + ((size_t)((net * 15 + 0) * 16) * 10) * 512 +
                       (size_t)l * 8;
    if (kq < 2) LOADF(bfA, base1, kq);
  }
  __syncthreads();

  for (int s = 0; s < 16; ++s) {
    // W0 frag prefetch: contiguous 1KB loads (consumed in tail)
    s16x8 w0pre0, w0pre1;
    if (s < 15) {
      const u16* W0g = W0f + net * W0F_NET + s * (5 * 512);
      w0pre0 = *(const s16x8*)(W0g + (size_t)kq * 512 + l * 8);
      if (kq == 0)
        w0pre1 = *(const s16x8*)(W0g + (size_t)4 * 512 + l * 8);
    }

    if (s > 0) {
      const int g = s - 1;
      const int ktn = (lb_of(s) + 63) >> 6;
      const int ktnN = (s < 15) ? ((lb_of(s + 1) + 63) >> 6) : 0;
      const u16* baseg = W1f + ((size_t)((net * 15 + g) * 16) * 10) * 512 +
                         (size_t)l * 8;
      const u16* basen = W1f + ((size_t)((net * 15 + s) * 16) * 10) * 512 +
                         (size_t)l * 8;
      // ALL waves: both nets' W2 frag loads, contiguous (used after bar2)
      s16x8 w2f[6];
#pragma unroll
      for (int c = 0; c < 3; ++c) {
        w2f[c] = *(const s16x8*)(W2f + ((size_t)(g * 3 + c) * 64 + l) * 8);
        w2f[3 + c] = *(const s16x8*)(W2f + (size_t)W2F_NET +
                                     ((size_t)(g * 3 + c) * 64 + l) * 8);
      }
      // GEMM, slots alternate A/B; i+1 prefetch issued at position i.
      f32x4 hacc[5] = {};
      if (kq + 4 < ktn)  LOADF(bfB, baseg, kq + 4);
      if (kq < ktn)      MFMAI(bfA, kq);
      if (kq + 8 < ktn)  LOADF(bfA, baseg, kq + 8);
      if (kq + 4 < ktn)  MFMAI(bfB, kq + 4);
      if (kq + 12 < ktn) LOADF(bfB, baseg, kq + 12);
      if (kq + 8 < ktn)  MFMAI(bfA, kq + 8);
      if (kq + 12 < ktn) MFMAI(bfB, kq + 12);
      // write partials
#pragma unroll
      for (int nf = 0; nf < 5; ++nf)
#pragma unroll
        for (int reg = 0; reg < 4; ++reg)
          sPart[net][kq][lk * 4 + reg][nf * 16 + lr] = hacc[nf][reg];
      // tail prefetch: next step's iter-0 lands under the step tail
      if (s < 15 && kq < ktnN) LOADF(bfA, basen, kq);
      barrier_lds();                       // bar1 (sPart visible)
      // reduce 4 partials + bias + elu -> sH1 (div-free mapping, 5/thread)
      {
        const int nn = tid >> 8;
        const int rr = (tid >> 4) & 15;
        const int u0 = tid & 15;
#pragma unroll
        for (int c = 0; c < 5; ++c) {
          int uu = c * 16 + u0;
          float v = sPart[nn][0][rr][uu] + sPart[nn][1][rr][uu] +
                    sPart[nn][2][rr][uu] + sPart[nn][3][rr][uu] +
                    sB1L[nn * 1200 + g * 80 + uu];
          sH1[nn][rr][uu] = f2bf(elu(v));
        }
      }
      barrier_lds();                       // bar2 (sH1 visible)
      // ML += h1grp @ W2g^T for BOTH nets, REDUNDANT in every wave
#pragma unroll
      for (int c = 0; c < 3; ++c) {
        s16x8 a0 = *(const s16x8*)(&sH1[0][lr][c * 32 + lk * 8]);
        mlacc0 = __builtin_amdgcn_mfma_f32_16x16x32_bf16(
            a0, w2f[c], mlacc0, 0, 0, 0);
        s16x8 a1v = *(const s16x8*)(&sH1[1][lr][c * 32 + lk * 8]);
        mlacc1 = __builtin_amdgcn_mfma_f32_16x16x32_bf16(
            a1v, w2f[3 + c], mlacc1, 0, 0, 0);
      }
    }
    // y update: EVERY wave computes y (lanes lr==s hold ML column s) and
    // writes yb (identical-value benign race). out/sLsum: wave 0 only.
    if (lr == s) {
#pragma unroll
      for (int reg = 0; reg < 4; ++reg) {
        int r = lk * 4 + reg;
        float mu = mlacc0[reg] + sB2[0][s];
        float lv = mlacc1[reg] + sB2[1][s];
        float ls = 0.5f * lv;
        float yv = (sX[r][s] - mu) / (__expf(ls) + EPSV);
        yb[r][s] = f2bf(yv);
        if (w == 0) {
          out[(size_t)(b0g + r) * 16 + s] = yv;
          float ns = sLsum[r] + ls;
          sLsum[r] = ns;
          if (s == 15) out[Bb * 16 + b0g + r] = ns;
        }
      }
    }
    // in-wave LDS ordering only: each wave wrote every yb row it reads.
    asm volatile("s_waitcnt lgkmcnt(0)" ::: "memory");
    if (s < 15) {
      // h0 group s = elu(y @ W0g^T + b0) -> h0L
      const int LbS = lb_of(s), szS = sz_of(s);
      s16x8 yfrag = *(const s16x8*)(&yb[lr][lk * 8]);
      {
        int unit = kq * 16 + lr;
        f32x4 h = __builtin_amdgcn_mfma_f32_16x16x32_bf16(
            yfrag, w0pre0, (f32x4){0.f, 0.f, 0.f, 0.f}, 0, 0, 0);
        if (unit < szS) {
          float bias = sB0L[net * 1200 + s * 80 + unit];
#pragma unroll
          for (int reg = 0; reg < 4; ++reg)
            h0L[net][lk * 4 + reg][LbS + unit] = f2bf(elu(h[reg] + bias));
        }
      }
      if (kq == 0) {
        int unit = 64 + lr;
        f32x4 h = __builtin_amdgcn_mfma_f32_16x16x32_bf16(
            yfrag, w0pre1, (f32x4){0.f, 0.f, 0.f, 0.f}, 0, 0, 0);
        if (unit < szS) {
          float bias = sB0L[net * 1200 + s * 80 + unit];
#pragma unroll
          for (int reg = 0; reg < 4; ++reg)
            h0L[net][lk * 4 + reg][LbS + unit] = f2bf(elu(h[reg] + bias));
        }
      }
      barrier_lds();                       // bar4 (h0L stable)
    }
  }
}

// --------------------------- launch ----------------------------------------

extern "C" void kernel_launch(void* const* d_in, const int* in_sizes, int n_in,
                              void* d_out, int out_size, void* d_ws, size_t ws_size,
                              hipStream_t stream) {
  const float* x     = (const float*)d_in[0];
  const float* mu_v0 = (const float*)d_in[1];
  const float* mu_g0 = (const float*)d_in[2];
  const float* mu_b0 = (const float*)d_in[3];
  const float* mu_v1 = (const float*)d_in[4];
  const float* mu_g1 = (const float*)d_in[5];
  const float* mu_b1 = (const float*)d_in[6];
  const float* mu_v2 = (const float*)d_in[7];
  const float* mu_g2 = (const float*)d_in[8];
  const float* mu_b2 = (const float*)d_in[9];
  const float* lv_v0 = (const float*)d_in[10];
  const float* lv_g0 = (const float*)d_in[11];
  const float* lv_b0 = (const float*)d_in[12];
  const float* lv_v1 = (const float*)d_in[13];
  const float* lv_g1 = (const float*)d_in[14];
  const float* lv_b1 = (const float*)d_in[15];
  const float* lv_v2 = (const float*)d_in[16];
  const float* lv_g2 = (const float*)d_in[17];
  const float* lv_b2 = (const float*)d_in[18];

  char* ws = (char*)d_ws;
  u16*   W1f = (u16*)(ws);                       // 4,915,200 B
  u16*   W2f = (u16*)(ws + 4915200);             //    92,160 B
  u16*   W0f = (u16*)(ws + 5007360);             //   153,600 B
  float* b1p = (float*)(ws + 5160960);           //     9,600 B
  float* b0p = (float*)(ws + 5170560);           //     9,600 B

  prep_all<<<600, 256, 0, stream>>>(
      mu_v0, mu_g0, mu_b0, mu_v1, mu_g1, mu_b1, mu_v2, mu_g2,
      lv_v0, lv_g0, lv_b0, lv_v1, lv_g1, lv_b1, lv_v2, lv_g2,
      W1f, W2f, W0f, b1p, b0p);

  afmade_main<<<128, 512, 0, stream>>>(W1f, W2f, W0f, b1p, b0p,
                                       mu_b2, lv_b2, x, (float*)d_out);
}